// Round 3
// baseline (295.125 us; speedup 1.0000x reference)
//
#include <hip/hip_runtime.h>

// Problem constants (from reference): E=1024, H=16, D=64, B=32, S=1024.
// ALGEBRA: softmax over a length-1 key axis == 1.0 exactly, so attention
// collapses: attn_out[b,s,:] = Wo @ (Wv @ (W_heat @ heat[b] + b_heat) + bv) + bo
// (independent of s; the img projection / Q / K path is dead code).
// Final: out[b,s,:] = LayerNorm(img_feat[b,s,:] + a[b,:]) * gamma + beta.
// All dtypes float32 (verified passing in R2).

#define E_DIM 1024
#define B_DIM 32
#define S_DIM 1024

// ---- GEMV stage: y[b,e] = dot(W[e,:], x[b,:]) + bias[e] -------------------
// One wave per (e, group-of-8-batches): W row is read by 4 waves total
// (vs 32 in R2) -> L2 traffic per stage ~132 MB instead of 256 MB.
// 4096 waves = 1024 blocks x 256 threads.
__global__ __launch_bounds__(256) void gemv8_f32(
        const float* __restrict__ W,    // [E,E] row-major
        const float* __restrict__ bias, // [E]
        const float* __restrict__ x,    // [B,E]
        float* __restrict__ y) {        // [B,E]
    const int w    = blockIdx.x * 4 + (threadIdx.x >> 6); // wave id [0,4096)
    const int lane = threadIdx.x & 63;
    const int e    = w >> 2;            // [0,1024)
    const int b0   = (w & 3) * 8;       // batch group base

    const float4* w4 = reinterpret_cast<const float4*>(W + (size_t)e * E_DIM);
    float acc[8] = {0.f, 0.f, 0.f, 0.f, 0.f, 0.f, 0.f, 0.f};

    #pragma unroll
    for (int p = 0; p < 4; ++p) {
        float4 wv = w4[p * 64 + lane];
        #pragma unroll
        for (int j = 0; j < 8; ++j) {
            const float4* x4 =
                reinterpret_cast<const float4*>(x + (size_t)(b0 + j) * E_DIM);
            float4 xv = x4[p * 64 + lane];
            acc[j] += wv.x * xv.x + wv.y * xv.y + wv.z * xv.z + wv.w * xv.w;
        }
    }

    const float be = bias[e];
    #pragma unroll
    for (int j = 0; j < 8; ++j) {
        float v = acc[j];
        #pragma unroll
        for (int off = 32; off; off >>= 1)
            v += __shfl_down(v, off, 64);
        if (lane == 0) y[(size_t)(b0 + j) * E_DIM + e] = v + be;
    }
}

// ---- Fused residual-add + LayerNorm ---------------------------------------
// One wave per row: 16 elems/lane via 4x float4, no LDS / no __syncthreads;
// __shfl_xor butterfly leaves mu/rstd in every lane.
__global__ __launch_bounds__(256) void resid_layernorm(
        const float* __restrict__ img,   // [B,S,E]
        const float* __restrict__ a,     // [B,E]
        const float* __restrict__ gamma, // [E]
        const float* __restrict__ beta,  // [E]
        float* __restrict__ out) {       // [B,S,E]
    const int row  = blockIdx.x * 4 + (threadIdx.x >> 6);  // [0, B*S)
    const int lane = threadIdx.x & 63;
    const int b    = row >> 10;          // / S

    const float4* ip = reinterpret_cast<const float4*>(img + (size_t)row * E_DIM);
    const float4* ap = reinterpret_cast<const float4*>(a + (size_t)b * E_DIM);

    float4 xv[4];
    float s = 0.f, q = 0.f;
    #pragma unroll
    for (int p = 0; p < 4; ++p) {
        float4 iv = ip[p * 64 + lane];
        float4 av = ap[p * 64 + lane];
        float4 x;
        x.x = iv.x + av.x;
        x.y = iv.y + av.y;
        x.z = iv.z + av.z;
        x.w = iv.w + av.w;
        xv[p] = x;
        s += x.x + x.y + x.z + x.w;
        q += x.x * x.x + x.y * x.y + x.z * x.z + x.w * x.w;
    }

    #pragma unroll
    for (int off = 32; off; off >>= 1) {
        s += __shfl_xor(s, off, 64);
        q += __shfl_xor(q, off, 64);
    }

    const float mu   = s * (1.0f / E_DIM);
    const float rstd = rsqrtf(q * (1.0f / E_DIM) - mu * mu + 1e-5f);

    const float4* gp = reinterpret_cast<const float4*>(gamma);
    const float4* bp = reinterpret_cast<const float4*>(beta);
    float4* op = reinterpret_cast<float4*>(out + (size_t)row * E_DIM);

    #pragma unroll
    for (int p = 0; p < 4; ++p) {
        float4 g  = gp[p * 64 + lane];
        float4 be = bp[p * 64 + lane];
        float4 o;
        o.x = (xv[p].x - mu) * rstd * g.x + be.x;
        o.y = (xv[p].y - mu) * rstd * g.y + be.y;
        o.z = (xv[p].z - mu) * rstd * g.z + be.z;
        o.w = (xv[p].w - mu) * rstd * g.w + be.w;
        op[p * 64 + lane] = o;
    }
}

extern "C" void kernel_launch(void* const* d_in, const int* in_sizes, int n_in,
                              void* d_out, int out_size, void* d_ws, size_t ws_size,
                              hipStream_t stream) {
    // setup_inputs order:
    // 0 img_feat [B,S,E], 1 heat_feat [B,E], 2 W_img, 3 b_img, 4 W_heat, 5 b_heat,
    // 6 Wq, 7 bq, 8 Wk, 9 bk, 10 Wv, 11 bv, 12 Wo, 13 bo, 14 gamma, 15 beta
    const float* img    = (const float*)d_in[0];
    const float* heat   = (const float*)d_in[1];
    const float* W_heat = (const float*)d_in[4];
    const float* b_heat = (const float*)d_in[5];
    const float* Wv     = (const float*)d_in[10];
    const float* bvv    = (const float*)d_in[11];
    const float* Wo     = (const float*)d_in[12];
    const float* bo     = (const float*)d_in[13];
    const float* gamma  = (const float*)d_in[14];
    const float* beta   = (const float*)d_in[15];
    float* out = (float*)d_out;

    // Workspace: 3 fp32 [B,E] buffers = 384 KiB.
    float* ws = (float*)d_ws;
    float* tt = ws;                      // W_heat stage
    float* vv = ws + B_DIM * E_DIM;      // Wv stage
    float* aa = ws + 2 * B_DIM * E_DIM;  // Wo stage (attn_out rows)

    // 4096 waves per GEMV stage -> 1024 blocks of 256 threads.
    gemv8_f32<<<1024, 256, 0, stream>>>(W_heat, b_heat, heat, tt);
    gemv8_f32<<<1024, 256, 0, stream>>>(Wv, bvv, tt, vv);
    gemv8_f32<<<1024, 256, 0, stream>>>(Wo, bo, vv, aa);

    // One wave per row: 32768 rows -> 8192 blocks of 256 threads.
    resid_layernorm<<<8192, 256, 0, stream>>>(img, aa, gamma, beta, out);
}